// Round 1
// baseline (292.609 us; speedup 1.0000x reference)
//
#include <hip/hip_runtime.h>
#include <hip/hip_bf16.h>

#define B_    512
#define N_    128
#define C_    4
#define E_    300
#define CE    1200
#define KP1   1216     // K padded to 38*32 for layer 1
#define H1_   512
#define H2_   256
#define MT    66048    // 512 * 129 rows (128 context + 1 event per batch)
#define LDSK  40       // LDS row stride in bf16 (32 + 8 pad; 80B = 16B-aligned)

typedef __attribute__((ext_vector_type(8))) short bf16x8;
typedef __attribute__((ext_vector_type(4))) float f32x4;
typedef __attribute__((ext_vector_type(4))) unsigned short us4;
typedef __attribute__((ext_vector_type(8))) unsigned short us8;

static __device__ inline unsigned short f2bf(float f) {
  unsigned int u = __float_as_uint(f);
  u += 0x7fffu + ((u >> 16) & 1u);        // RNE
  return (unsigned short)(u >> 16);
}
static __device__ inline float bf2f(unsigned short h) {
  return __uint_as_float(((unsigned int)h) << 16);
}

// ---------------------------------------------------------------- weights->bf16
__global__ void convert_w(const float* __restrict__ W1, const float* __restrict__ W2,
                          unsigned short* __restrict__ W1b, unsigned short* __restrict__ W2b) {
  int i = blockIdx.x * 256 + threadIdx.x;
  const int tot1 = H1_ * KP1;          // 622592
  const int tot2 = H2_ * H1_;          // 131072
  if (i < tot1) {
    int r = i / KP1, k = i - r * KP1;
    W1b[i] = (k < CE) ? f2bf(W1[r * CE + k]) : (unsigned short)0;
  } else if (i < tot1 + tot2) {
    int j = i - tot1;
    W2b[j] = f2bf(W2[j]);
  }
}

// ---------------------------------------------------------------- GEMM1: gather + X@W1^T, relu
// grid: (MT/64) * 2 blocks; block 256 threads (4 waves). Tile 64 rows x 256 cols.
__global__ __launch_bounds__(256) void gemm1_k(
    const float* __restrict__ table, const unsigned short* __restrict__ W1b,
    const float* __restrict__ b1, const int* __restrict__ bev, const int* __restrict__ bctx,
    unsigned short* __restrict__ H1buf) {
  __shared__ unsigned short As[64 * LDSK];
  __shared__ unsigned short Bs[256 * LDSK];

  const int tid  = threadIdx.x;
  const int lane = tid & 63;
  const int w    = tid >> 6;
  const int mt   = blockIdx.x >> 1;
  const int nb   = blockIdx.x & 1;
  const int m0   = mt * 64;
  const int n0   = nb * 256;

  // A staging: thread -> (row = tid>>2, 8 k-elems at (tid&3)*8)
  const int arow  = tid >> 2;
  const int apart = tid & 3;
  const int mrow  = m0 + arow;
  const int bidx  = mrow / 129;
  const int nidx  = mrow - bidx * 129;
  int idx[4];
  {
    const int* p = (nidx < 128) ? (bctx + ((size_t)bidx * 128 + nidx) * 4)
                                : (bev + (size_t)bidx * 4);
    idx[0] = p[0]; idx[1] = p[1]; idx[2] = p[2]; idx[3] = p[3];
  }

  f32x4 acc[4][4];
#pragma unroll
  for (int mi = 0; mi < 4; ++mi)
#pragma unroll
    for (int ni = 0; ni < 4; ++ni)
#pragma unroll
      for (int r = 0; r < 4; ++r) acc[mi][ni][r] = 0.f;

  const int fr = lane & 15;
  const int fg = lane >> 4;

  for (int k0 = 0; k0 < KP1; k0 += 32) {
    // ---- issue global loads (regs) before barrier
    float fa[8];
#pragma unroll
    for (int h = 0; h < 2; ++h) {
      int kk = k0 + apart * 8 + h * 4;
      float4 v = make_float4(0.f, 0.f, 0.f, 0.f);
      if (kk < CE) {
        int c = kk / 300;
        int e = kk - c * 300;
        v = *reinterpret_cast<const float4*>(table + (size_t)idx[c] * 300 + e);
      }
      fa[h * 4 + 0] = v.x; fa[h * 4 + 1] = v.y; fa[h * 4 + 2] = v.z; fa[h * 4 + 3] = v.w;
    }
    us8 bvv[4];
#pragma unroll
    for (int i = 0; i < 4; ++i) {
      int ch = i * 256 + tid;
      int brow = ch >> 2, bpart = ch & 3;
      bvv[i] = *reinterpret_cast<const us8*>(&W1b[(size_t)(n0 + brow) * KP1 + k0 + bpart * 8]);
    }
    __syncthreads();   // previous iteration's frag reads done
    {
      us8 av;
#pragma unroll
      for (int j = 0; j < 8; ++j) av[j] = f2bf(fa[j]);
      *reinterpret_cast<us8*>(&As[arow * LDSK + apart * 8]) = av;
    }
#pragma unroll
    for (int i = 0; i < 4; ++i) {
      int ch = i * 256 + tid;
      int brow = ch >> 2, bpart = ch & 3;
      *reinterpret_cast<us8*>(&Bs[brow * LDSK + bpart * 8]) = bvv[i];
    }
    __syncthreads();   // tile ready
    bf16x8 af[4], bfr[4];
#pragma unroll
    for (int mi = 0; mi < 4; ++mi)
      af[mi] = *reinterpret_cast<const bf16x8*>(&As[(mi * 16 + fr) * LDSK + fg * 8]);
#pragma unroll
    for (int ni = 0; ni < 4; ++ni)
      bfr[ni] = *reinterpret_cast<const bf16x8*>(&Bs[(w * 64 + ni * 16 + fr) * LDSK + fg * 8]);
#pragma unroll
    for (int mi = 0; mi < 4; ++mi)
#pragma unroll
      for (int ni = 0; ni < 4; ++ni)
        acc[mi][ni] = __builtin_amdgcn_mfma_f32_16x16x32_bf16(af[mi], bfr[ni], acc[mi][ni], 0, 0, 0);
  }

  // epilogue: bias + relu -> bf16
  float bb[4];
#pragma unroll
  for (int ni = 0; ni < 4; ++ni) bb[ni] = b1[n0 + w * 64 + ni * 16 + fr];
#pragma unroll
  for (int mi = 0; mi < 4; ++mi)
#pragma unroll
    for (int ni = 0; ni < 4; ++ni)
#pragma unroll
      for (int r = 0; r < 4; ++r) {
        float v = fmaxf(acc[mi][ni][r] + bb[ni], 0.f);
        int row = m0 + mi * 16 + fg * 4 + r;
        int col = n0 + w * 64 + ni * 16 + fr;
        H1buf[(size_t)row * H1_ + col] = f2bf(v);
      }
}

// ---------------------------------------------------------------- GEMM2: H1@W2^T, relu
// grid: MT/64 blocks; block 256 threads. Tile 64 rows x 256 cols (full H2).
__global__ __launch_bounds__(256) void gemm2_k(
    const unsigned short* __restrict__ H1buf, const unsigned short* __restrict__ W2b,
    const float* __restrict__ b2, unsigned short* __restrict__ RPR) {
  __shared__ unsigned short As[64 * LDSK];
  __shared__ unsigned short Bs[256 * LDSK];

  const int tid  = threadIdx.x;
  const int lane = tid & 63;
  const int w    = tid >> 6;
  const int m0   = blockIdx.x * 64;
  const int arow = tid >> 2, apart = tid & 3;
  const int fr = lane & 15, fg = lane >> 4;

  f32x4 acc[4][4];
#pragma unroll
  for (int mi = 0; mi < 4; ++mi)
#pragma unroll
    for (int ni = 0; ni < 4; ++ni)
#pragma unroll
      for (int r = 0; r < 4; ++r) acc[mi][ni][r] = 0.f;

  for (int k0 = 0; k0 < H1_; k0 += 32) {
    us8 av = *reinterpret_cast<const us8*>(&H1buf[(size_t)(m0 + arow) * H1_ + k0 + apart * 8]);
    us8 bvv[4];
#pragma unroll
    for (int i = 0; i < 4; ++i) {
      int ch = i * 256 + tid;
      int brow = ch >> 2, bpart = ch & 3;
      bvv[i] = *reinterpret_cast<const us8*>(&W2b[(size_t)brow * H1_ + k0 + bpart * 8]);
    }
    __syncthreads();
    *reinterpret_cast<us8*>(&As[arow * LDSK + apart * 8]) = av;
#pragma unroll
    for (int i = 0; i < 4; ++i) {
      int ch = i * 256 + tid;
      int brow = ch >> 2, bpart = ch & 3;
      *reinterpret_cast<us8*>(&Bs[brow * LDSK + bpart * 8]) = bvv[i];
    }
    __syncthreads();
    bf16x8 af[4], bfr[4];
#pragma unroll
    for (int mi = 0; mi < 4; ++mi)
      af[mi] = *reinterpret_cast<const bf16x8*>(&As[(mi * 16 + fr) * LDSK + fg * 8]);
#pragma unroll
    for (int ni = 0; ni < 4; ++ni)
      bfr[ni] = *reinterpret_cast<const bf16x8*>(&Bs[(w * 64 + ni * 16 + fr) * LDSK + fg * 8]);
#pragma unroll
    for (int mi = 0; mi < 4; ++mi)
#pragma unroll
      for (int ni = 0; ni < 4; ++ni)
        acc[mi][ni] = __builtin_amdgcn_mfma_f32_16x16x32_bf16(af[mi], bfr[ni], acc[mi][ni], 0, 0, 0);
  }

  float bb[4];
#pragma unroll
  for (int ni = 0; ni < 4; ++ni) bb[ni] = b2[w * 64 + ni * 16 + fr];
#pragma unroll
  for (int mi = 0; mi < 4; ++mi)
#pragma unroll
    for (int ni = 0; ni < 4; ++ni)
#pragma unroll
      for (int r = 0; r < 4; ++r) {
        float v = fmaxf(acc[mi][ni][r] + bb[ni], 0.f);
        int row = m0 + mi * 16 + fg * 4 + r;
        int col = w * 64 + ni * 16 + fr;
        RPR[(size_t)row * H2_ + col] = f2bf(v);
      }
}

// ---------------------------------------------------------------- cosine trans: [B,128]
__global__ __launch_bounds__(256) void trans_k(const unsigned short* __restrict__ RPR,
                                               float* __restrict__ TRANS) {
  const int b = blockIdx.x, tid = threadIdx.x, lane = tid & 63, w = tid >> 6;
  const unsigned short* ev = RPR + ((size_t)b * 129 + 128) * H2_;
  us4 e4 = *reinterpret_cast<const us4*>(&ev[lane * 4]);
  float e0 = bf2f(e4[0]), e1 = bf2f(e4[1]), e2 = bf2f(e4[2]), e3 = bf2f(e4[3]);
  float ess = e0 * e0 + e1 * e1 + e2 * e2 + e3 * e3;
#pragma unroll
  for (int off = 32; off; off >>= 1) ess += __shfl_xor(ess, off);
  const float inv_e = 1.f / fmaxf(sqrtf(ess), 1e-12f);

  for (int n = w; n < 128; n += 4) {
    const unsigned short* cv = RPR + ((size_t)b * 129 + n) * H2_;
    us4 c4 = *reinterpret_cast<const us4*>(&cv[lane * 4]);
    float c0 = bf2f(c4[0]), c1 = bf2f(c4[1]), c2 = bf2f(c4[2]), c3 = bf2f(c4[3]);
    float dot = c0 * e0 + c1 * e1 + c2 * e2 + c3 * e3;
    float ss  = c0 * c0 + c1 * c1 + c2 * c2 + c3 * c3;
#pragma unroll
    for (int off = 32; off; off >>= 1) {
      dot += __shfl_xor(dot, off);
      ss  += __shfl_xor(ss, off);
    }
    if (lane == 0)
      TRANS[b * 128 + n] = dot * inv_e * (1.f / fmaxf(sqrtf(ss), 1e-12f));
  }
}

// ---------------------------------------------------------------- final: variances, dist, KNRM, linear, sigmoid
__global__ __launch_bounds__(128) void final_k(
    const float* __restrict__ table, const float* __restrict__ Wv, const float* __restrict__ bv,
    const float* __restrict__ Wc, const float* __restrict__ bc, const int* __restrict__ bev,
    const float* __restrict__ bdist, const float* __restrict__ bfeat,
    const float* __restrict__ TRANS, float* __restrict__ out) {
  const int b = blockIdx.x, tid = threadIdx.x;
  __shared__ float pred[E_];
  __shared__ float var_s[9];
  __shared__ float pool_s[2][11];

  const float MU[11]  = {1.0f, 0.9f, 0.7f, 0.5f, 0.3f, 0.1f, -0.1f, -0.3f, -0.5f, -0.7f, -0.9f};
  const float IS2[11] = {500000.f, 50.f, 50.f, 50.f, 50.f, 50.f, 50.f, 50.f, 50.f, 50.f, 50.f};

  const int prow = bev[b * 4 + 1];
  for (int e = tid; e < E_; e += 128) pred[e] = table[(size_t)prow * E_ + e];
  __syncthreads();

  if (tid < 9) {
    float s = bv[tid];
    for (int e = 0; e < E_; ++e) s += pred[e] * Wv[tid * E_ + e];
    var_s[tid] = fmaxf(s, 0.f) + log1pf(expf(-fabsf(s)));   // softplus
  }

  // KNRM pooling over 128 context positions
  float t = TRANS[b * 128 + tid];
  float kv[11];
#pragma unroll
  for (int kk = 0; kk < 11; ++kk) {
    float u = t - MU[kk];
    kv[kk] = expf(-u * u * IS2[kk]);
  }
#pragma unroll
  for (int off = 32; off; off >>= 1)
#pragma unroll
    for (int kk = 0; kk < 11; ++kk) kv[kk] += __shfl_xor(kv[kk], off);
  const int w = tid >> 6, lane = tid & 63;
  if (lane == 0)
#pragma unroll
    for (int kk = 0; kk < 11; ++kk) pool_s[w][kk] = kv[kk];
  __syncthreads();

  if (tid == 0) {
    float score = bc[0];
    for (int j = 0; j < 9; ++j) {
      float d = bdist[b * 9 + j];
      score += Wc[j] * expf(-(d * d) / var_s[j]);
    }
    for (int i = 0; i < 8; ++i) score += Wc[9 + i] * bfeat[b * 8 + i];
    for (int kk = 0; kk < 11; ++kk) {
      float p = fmaxf(pool_s[0][kk] + pool_s[1][kk], 1e-10f);
      score += Wc[17 + kk] * (0.01f * logf(p));
    }
    out[b] = 1.f / (1.f + expf(-score));
  }
}

// ----------------------------------------------------------------
extern "C" void kernel_launch(void* const* d_in, const int* in_sizes, int n_in,
                              void* d_out, int out_size, void* d_ws, size_t ws_size,
                              hipStream_t stream) {
  const float* table = (const float*)d_in[0];
  const float* W1    = (const float*)d_in[1];
  const float* b1    = (const float*)d_in[2];
  const float* W2    = (const float*)d_in[3];
  const float* b2    = (const float*)d_in[4];
  const float* Wv    = (const float*)d_in[5];
  const float* bv    = (const float*)d_in[6];
  const float* Wc    = (const float*)d_in[7];
  const float* bc    = (const float*)d_in[8];
  const int*   bev   = (const int*)d_in[9];
  const float* bfeat = (const float*)d_in[10];
  const float* bdist = (const float*)d_in[11];
  const int*   bctx  = (const int*)d_in[12];
  float* out = (float*)d_out;

  char* ws = (char*)d_ws;
  size_t need = (size_t)H1_ * KP1 * 2 + (size_t)H2_ * H1_ * 2 +
                (size_t)MT * H1_ * 2 + (size_t)MT * H2_ * 2 + (size_t)B_ * N_ * 4;
  if (ws_size < need) {                       // loud, distinguishable failure
    hipMemsetAsync(d_out, 0xBF, (size_t)out_size * 4, stream);
    return;
  }
  unsigned short* W1b   = (unsigned short*)ws; ws += (size_t)H1_ * KP1 * 2;
  unsigned short* W2b   = (unsigned short*)ws; ws += (size_t)H2_ * H1_ * 2;
  unsigned short* H1buf = (unsigned short*)ws; ws += (size_t)MT * H1_ * 2;
  unsigned short* RPR   = (unsigned short*)ws; ws += (size_t)MT * H2_ * 2;
  float*          TRANS = (float*)ws;          ws += (size_t)B_ * N_ * 4;

  hipLaunchKernelGGL(convert_w, dim3(2944), dim3(256), 0, stream, W1, W2, W1b, W2b);
  hipLaunchKernelGGL(gemm1_k, dim3((MT / 64) * 2), dim3(256), 0, stream,
                     table, W1b, b1, bev, bctx, H1buf);
  hipLaunchKernelGGL(gemm2_k, dim3(MT / 64), dim3(256), 0, stream, H1buf, W2b, b2, RPR);
  hipLaunchKernelGGL(trans_k, dim3(B_), dim3(256), 0, stream, RPR, TRANS);
  hipLaunchKernelGGL(final_k, dim3(B_), dim3(128), 0, stream,
                     table, Wv, bv, Wc, bc, bev, bdist, bfeat, TRANS, out);
}

// Round 2
// 251.964 us; speedup vs baseline: 1.1613x; 1.1613x over previous
//
#include <hip/hip_runtime.h>
#include <hip/hip_bf16.h>

#define B_    512
#define N_    128
#define E_    300
#define CE    1200
#define KP1   1216     // layer-1 K padded to 38*32
#define H1_   512
#define H2_   256
#define MT    66048    // 512 * 129 rows
#define T4    3750075  // table float4 chunks (15,000,300 / 4)

typedef __attribute__((ext_vector_type(8))) short bf16x8;
typedef __attribute__((ext_vector_type(4))) float f32x4;
typedef __attribute__((ext_vector_type(4))) unsigned short us4;

static __device__ __forceinline__ unsigned short f2bf(float f) {
  unsigned int u = __float_as_uint(f);
  u += 0x7fffu + ((u >> 16) & 1u);        // RNE
  return (unsigned short)(u >> 16);
}
static __device__ __forceinline__ float bf2f(unsigned short h) {
  return __uint_as_float(((unsigned int)h) << 16);
}

// async global->LDS. LDS dest is WAVE-UNIFORM base + lane*size (pass base only).
static __device__ __forceinline__ void gl16(const void* g, void* l) {
  __builtin_amdgcn_global_load_lds((const __attribute__((address_space(1))) unsigned int*)g,
                                   (__attribute__((address_space(3))) unsigned int*)l, 16, 0, 0);
}
static __device__ __forceinline__ void gl4(const void* g, void* l) {
  __builtin_amdgcn_global_load_lds((const __attribute__((address_space(1))) unsigned int*)g,
                                   (__attribute__((address_space(3))) unsigned int*)l, 4, 0, 0);
}

// ---------------------------------------------------------------- all fp32->bf16 conversions
__global__ __launch_bounds__(256) void convert_k(
    const float* __restrict__ table, const float* __restrict__ W1, const float* __restrict__ W2,
    unsigned short* __restrict__ tb, unsigned short* __restrict__ W1b,
    unsigned short* __restrict__ W2b, unsigned short* __restrict__ zpad) {
  const int tot1 = H1_ * KP1;          // 622592
  const int tot2 = H2_ * H1_;          // 131072
  int i = blockIdx.x * 256 + threadIdx.x;
  if (i < T4) {
    float4 v = reinterpret_cast<const float4*>(table)[i];
    us4 o; o[0] = f2bf(v.x); o[1] = f2bf(v.y); o[2] = f2bf(v.z); o[3] = f2bf(v.w);
    reinterpret_cast<us4*>(tb)[i] = o;
  } else if (i < T4 + tot1) {
    int j = i - T4; int r = j / KP1, k = j - r * KP1;
    W1b[j] = (k < CE) ? f2bf(W1[r * CE + k]) : (unsigned short)0;
  } else if (i < T4 + tot1 + tot2) {
    int j = i - T4 - tot1;
    W2b[j] = f2bf(W2[j]);
  } else if (i < T4 + tot1 + tot2 + 64) {
    zpad[i - T4 - tot1 - tot2] = 0;
  }
}

// ---------------------------------------------------------------- GEMM1: gather + X@W1^T, relu
// tile 64M x 512N (full H1), BK=32, 512 threads = 8 waves, wave -> 64M x 64N.
// All staging via global_load_lds; LDS linear [rows][32] with 16B-chunk XOR swizzle
// (p16 ^= (row>>1)&3) applied on the global source AND on ds_read (rule 21).
__global__ __launch_bounds__(512) void gemm1_k(
    const unsigned short* __restrict__ tb, const unsigned short* __restrict__ W1b,
    const float* __restrict__ b1, const int* __restrict__ bev, const int* __restrict__ bctx,
    const unsigned short* __restrict__ zpad, unsigned short* __restrict__ H1buf) {
  __shared__ unsigned short As[64 * 32];    //  4 KB
  __shared__ unsigned short Bs[512 * 32];   // 32 KB

  const int tid  = threadIdx.x;
  const int lane = tid & 63;
  const int w    = tid >> 6;
  const int m0   = blockIdx.x * 64;
  const int fr   = lane & 15, fg = lane >> 4;

  // ---- A staging geometry: dword chunk c = h*512 + tid, h in {0,1}
  //      row = c>>4 = (tid>>4) + 32h ; d = tid&15 ; p16 = d>>2 ; w4 = d&3
  const int rA   = tid >> 4;                 // 0..31
  const int p16a = (tid >> 2) & 3;
  const int w4a  = tid & 3;
  const int l16a = p16a ^ ((rA >> 1) & 3);   // same for h=0,1 (+32 rows -> +16 in row>>1, ==0 mod 4)
  const int eoffA = l16a * 8 + w4a * 2;      // element offset within 32-wide k-slice

  int idxa[2][4];
#pragma unroll
  for (int h = 0; h < 2; ++h) {
    int mrow = m0 + rA + h * 32;
    int bidx = mrow / 129, nidx = mrow - bidx * 129;
    const int* p = (nidx < 128) ? bctx + ((size_t)bidx * 128 + nidx) * 4
                                : bev + (size_t)bidx * 4;
    idxa[h][0] = p[0]; idxa[h][1] = p[1]; idxa[h][2] = p[2]; idxa[h][3] = p[3];
  }

  // ---- B staging geometry: 16B chunk c = i*512 + tid, i in 0..3
  //      row = c>>2 = 128i + (tid>>2) ; p16 = tid&3
  const int rB   = tid >> 2;
  const int l16b = (tid & 3) ^ ((rB >> 1) & 3);   // +128 rows -> +64 in row>>1, ==0 mod 4
  const unsigned short* bsrc = W1b + (size_t)rB * KP1 + l16b * 8;

  const int p16f = fg ^ ((fr >> 1) & 3);    // fragment-read swizzle (row low bits = fr)

  f32x4 acc[4][4];
#pragma unroll
  for (int mi = 0; mi < 4; ++mi)
#pragma unroll
    for (int ni = 0; ni < 4; ++ni)
#pragma unroll
      for (int r = 0; r < 4; ++r) acc[mi][ni][r] = 0.f;

  for (int k0 = 0; k0 < KP1; k0 += 32) {
    __syncthreads();                       // previous iteration's frag reads done
    // ---- stage A (2 x 4B per thread)
    {
      int kk = k0 + eoffA;
      if (kk >= CE) {
#pragma unroll
        for (int h = 0; h < 2; ++h) gl4(zpad, As + (size_t)(h * 512 + w * 64) * 2);
      } else {
        int c_ = (kk >= 900) ? 3 : (kk >= 600) ? 2 : (kk >= 300) ? 1 : 0;
        int e  = kk - c_ * 300;
#pragma unroll
        for (int h = 0; h < 2; ++h)
          gl4(tb + (size_t)idxa[h][c_] * 300 + e, As + (size_t)(h * 512 + w * 64) * 2);
      }
    }
    // ---- stage B (4 x 16B per thread)
#pragma unroll
    for (int i = 0; i < 4; ++i)
      gl16(bsrc + (size_t)i * 128 * KP1 + k0, Bs + (size_t)(i * 512 + w * 64) * 8);
    __syncthreads();                       // compiler drains vmcnt before s_barrier

    bf16x8 af[4], bfr[4];
#pragma unroll
    for (int mi = 0; mi < 4; ++mi)
      af[mi] = *reinterpret_cast<const bf16x8*>(&As[(mi * 16 + fr) * 32 + p16f * 8]);
#pragma unroll
    for (int ni = 0; ni < 4; ++ni)
      bfr[ni] = *reinterpret_cast<const bf16x8*>(&Bs[(w * 64 + ni * 16 + fr) * 32 + p16f * 8]);
#pragma unroll
    for (int mi = 0; mi < 4; ++mi)
#pragma unroll
      for (int ni = 0; ni < 4; ++ni)
        acc[mi][ni] = __builtin_amdgcn_mfma_f32_16x16x32_bf16(af[mi], bfr[ni], acc[mi][ni], 0, 0, 0);
  }

  float bb[4];
#pragma unroll
  for (int ni = 0; ni < 4; ++ni) bb[ni] = b1[w * 64 + ni * 16 + fr];
#pragma unroll
  for (int mi = 0; mi < 4; ++mi)
#pragma unroll
    for (int ni = 0; ni < 4; ++ni)
#pragma unroll
      for (int r = 0; r < 4; ++r) {
        float v = fmaxf(acc[mi][ni][r] + bb[ni], 0.f);
        int row = m0 + mi * 16 + fg * 4 + r;
        int col = w * 64 + ni * 16 + fr;
        H1buf[(size_t)row * H1_ + col] = f2bf(v);
      }
}

// ---------------------------------------------------------------- GEMM2: H1@W2^T, relu
// tile 64M x 256N (full H2), BK=32, 256 threads = 4 waves, wave -> 64M x 64N.
__global__ __launch_bounds__(256) void gemm2_k(
    const unsigned short* __restrict__ H1buf, const unsigned short* __restrict__ W2b,
    const float* __restrict__ b2, unsigned short* __restrict__ RPR) {
  __shared__ unsigned short As[64 * 32];    //  4 KB
  __shared__ unsigned short Bs[256 * 32];   // 16 KB

  const int tid  = threadIdx.x;
  const int lane = tid & 63;
  const int w    = tid >> 6;
  const int m0   = blockIdx.x * 64;
  const int fr   = lane & 15, fg = lane >> 4;

  // A: 256 chunks16: c = tid: row = tid>>2, p16 = tid&3. B: c = i*256+tid: row = 64i + (tid>>2).
  const int rC   = tid >> 2;
  const int l16  = (tid & 3) ^ ((rC >> 1) & 3);   // same for A and B (row low bits match)
  const unsigned short* asrc = H1buf + (size_t)(m0 + rC) * H1_ + l16 * 8;
  const unsigned short* bsrc = W2b + (size_t)rC * H1_ + l16 * 8;
  const int p16f = fg ^ ((fr >> 1) & 3);

  f32x4 acc[4][4];
#pragma unroll
  for (int mi = 0; mi < 4; ++mi)
#pragma unroll
    for (int ni = 0; ni < 4; ++ni)
#pragma unroll
      for (int r = 0; r < 4; ++r) acc[mi][ni][r] = 0.f;

  for (int k0 = 0; k0 < H1_; k0 += 32) {
    __syncthreads();
    gl16(asrc + k0, As + (size_t)(w * 64) * 8);
#pragma unroll
    for (int i = 0; i < 4; ++i)
      gl16(bsrc + (size_t)i * 64 * H1_ + k0, Bs + (size_t)(i * 256 + w * 64) * 8);
    __syncthreads();

    bf16x8 af[4], bfr[4];
#pragma unroll
    for (int mi = 0; mi < 4; ++mi)
      af[mi] = *reinterpret_cast<const bf16x8*>(&As[(mi * 16 + fr) * 32 + p16f * 8]);
#pragma unroll
    for (int ni = 0; ni < 4; ++ni)
      bfr[ni] = *reinterpret_cast<const bf16x8*>(&Bs[(w * 64 + ni * 16 + fr) * 32 + p16f * 8]);
#pragma unroll
    for (int mi = 0; mi < 4; ++mi)
#pragma unroll
      for (int ni = 0; ni < 4; ++ni)
        acc[mi][ni] = __builtin_amdgcn_mfma_f32_16x16x32_bf16(af[mi], bfr[ni], acc[mi][ni], 0, 0, 0);
  }

  float bb[4];
#pragma unroll
  for (int ni = 0; ni < 4; ++ni) bb[ni] = b2[w * 64 + ni * 16 + fr];
#pragma unroll
  for (int mi = 0; mi < 4; ++mi)
#pragma unroll
    for (int ni = 0; ni < 4; ++ni)
#pragma unroll
      for (int r = 0; r < 4; ++r) {
        float v = fmaxf(acc[mi][ni][r] + bb[ni], 0.f);
        int row = m0 + mi * 16 + fg * 4 + r;
        int col = w * 64 + ni * 16 + fr;
        RPR[(size_t)row * H2_ + col] = f2bf(v);
      }
}

// ---------------------------------------------------------------- cosine trans: [B,128]
__global__ __launch_bounds__(256) void trans_k(const unsigned short* __restrict__ RPR,
                                               float* __restrict__ TRANS) {
  const int b = blockIdx.x, tid = threadIdx.x, lane = tid & 63, w = tid >> 6;
  const unsigned short* ev = RPR + ((size_t)b * 129 + 128) * H2_;
  us4 e4 = *reinterpret_cast<const us4*>(&ev[lane * 4]);
  float e0 = bf2f(e4[0]), e1 = bf2f(e4[1]), e2 = bf2f(e4[2]), e3 = bf2f(e4[3]);
  float ess = e0 * e0 + e1 * e1 + e2 * e2 + e3 * e3;
#pragma unroll
  for (int off = 32; off; off >>= 1) ess += __shfl_xor(ess, off);
  const float inv_e = 1.f / fmaxf(sqrtf(ess), 1e-12f);

  for (int n = w; n < 128; n += 4) {
    const unsigned short* cv = RPR + ((size_t)b * 129 + n) * H2_;
    us4 c4 = *reinterpret_cast<const us4*>(&cv[lane * 4]);
    float c0 = bf2f(c4[0]), c1 = bf2f(c4[1]), c2 = bf2f(c4[2]), c3 = bf2f(c4[3]);
    float dot = c0 * e0 + c1 * e1 + c2 * e2 + c3 * e3;
    float ss  = c0 * c0 + c1 * c1 + c2 * c2 + c3 * c3;
#pragma unroll
    for (int off = 32; off; off >>= 1) {
      dot += __shfl_xor(dot, off);
      ss  += __shfl_xor(ss, off);
    }
    if (lane == 0)
      TRANS[b * 128 + n] = dot * inv_e * (1.f / fmaxf(sqrtf(ss), 1e-12f));
  }
}

// ---------------------------------------------------------------- final: variances, dist, KNRM, linear, sigmoid
__global__ __launch_bounds__(128) void final_k(
    const float* __restrict__ table, const float* __restrict__ Wv, const float* __restrict__ bv,
    const float* __restrict__ Wc, const float* __restrict__ bc, const int* __restrict__ bev,
    const float* __restrict__ bdist, const float* __restrict__ bfeat,
    const float* __restrict__ TRANS, float* __restrict__ out) {
  const int b = blockIdx.x, tid = threadIdx.x;
  __shared__ float pred[E_];
  __shared__ float var_s[9];
  __shared__ float pool_s[2][11];

  const float MU[11]  = {1.0f, 0.9f, 0.7f, 0.5f, 0.3f, 0.1f, -0.1f, -0.3f, -0.5f, -0.7f, -0.9f};
  const float IS2[11] = {500000.f, 50.f, 50.f, 50.f, 50.f, 50.f, 50.f, 50.f, 50.f, 50.f, 50.f};

  const int prow = bev[b * 4 + 1];
  for (int e = tid; e < E_; e += 128) pred[e] = table[(size_t)prow * E_ + e];
  __syncthreads();

  if (tid < 9) {
    float s = bv[tid];
    for (int e = 0; e < E_; ++e) s += pred[e] * Wv[tid * E_ + e];
    var_s[tid] = fmaxf(s, 0.f) + log1pf(expf(-fabsf(s)));   // softplus
  }

  float t = TRANS[b * 128 + tid];
  float kv[11];
#pragma unroll
  for (int kk = 0; kk < 11; ++kk) {
    float u = t - MU[kk];
    kv[kk] = expf(-u * u * IS2[kk]);
  }
#pragma unroll
  for (int off = 32; off; off >>= 1)
#pragma unroll
    for (int kk = 0; kk < 11; ++kk) kv[kk] += __shfl_xor(kv[kk], off);
  const int w = tid >> 6, lane = tid & 63;
  if (lane == 0)
#pragma unroll
    for (int kk = 0; kk < 11; ++kk) pool_s[w][kk] = kv[kk];
  __syncthreads();

  if (tid == 0) {
    float score = bc[0];
    for (int j = 0; j < 9; ++j) {
      float d = bdist[b * 9 + j];
      score += Wc[j] * expf(-(d * d) / var_s[j]);
    }
    for (int i = 0; i < 8; ++i) score += Wc[9 + i] * bfeat[b * 8 + i];
    for (int kk = 0; kk < 11; ++kk) {
      float p = fmaxf(pool_s[0][kk] + pool_s[1][kk], 1e-10f);
      score += Wc[17 + kk] * (0.01f * logf(p));
    }
    out[b] = 1.f / (1.f + expf(-score));
  }
}

// ----------------------------------------------------------------
extern "C" void kernel_launch(void* const* d_in, const int* in_sizes, int n_in,
                              void* d_out, int out_size, void* d_ws, size_t ws_size,
                              hipStream_t stream) {
  const float* table = (const float*)d_in[0];
  const float* W1    = (const float*)d_in[1];
  const float* b1    = (const float*)d_in[2];
  const float* W2    = (const float*)d_in[3];
  const float* b2    = (const float*)d_in[4];
  const float* Wv    = (const float*)d_in[5];
  const float* bv    = (const float*)d_in[6];
  const float* Wc    = (const float*)d_in[7];
  const float* bc    = (const float*)d_in[8];
  const int*   bev   = (const int*)d_in[9];
  const float* bfeat = (const float*)d_in[10];
  const float* bdist = (const float*)d_in[11];
  const int*   bctx  = (const int*)d_in[12];
  float* out = (float*)d_out;

  auto align64 = [](size_t x) { return (x + 63) & ~(size_t)63; };
  size_t off = 0;
  size_t o_tb    = off; off += align64((size_t)T4 * 4 * 2);          // 30.0 MB bf16 table
  size_t o_W1b   = off; off += align64((size_t)H1_ * KP1 * 2);       //  1.25 MB
  size_t o_W2b   = off; off += align64((size_t)H2_ * H1_ * 2);       //  0.26 MB
  size_t o_zpad  = off; off += align64(128);
  size_t o_H1    = off; off += align64((size_t)MT * H1_ * 2);        // 67.6 MB
  size_t o_RPR   = off; off += align64((size_t)MT * H2_ * 2);        // 33.8 MB
  size_t o_TR    = off; off += align64((size_t)B_ * N_ * 4);         //  0.26 MB
  if (ws_size < off) {                       // loud, distinguishable failure
    hipMemsetAsync(d_out, 0xBF, (size_t)out_size * 4, stream);
    return;
  }
  char* ws = (char*)d_ws;
  unsigned short* tb    = (unsigned short*)(ws + o_tb);
  unsigned short* W1b   = (unsigned short*)(ws + o_W1b);
  unsigned short* W2b   = (unsigned short*)(ws + o_W2b);
  unsigned short* zpad  = (unsigned short*)(ws + o_zpad);
  unsigned short* H1buf = (unsigned short*)(ws + o_H1);
  unsigned short* RPR   = (unsigned short*)(ws + o_RPR);
  float*          TRANS = (float*)(ws + o_TR);

  const int conv_items = T4 + H1_ * KP1 + H2_ * H1_ + 64;
  hipLaunchKernelGGL(convert_k, dim3((conv_items + 255) / 256), dim3(256), 0, stream,
                     table, W1, W2, tb, W1b, W2b, zpad);
  hipLaunchKernelGGL(gemm1_k, dim3(MT / 64), dim3(512), 0, stream,
                     tb, W1b, b1, bev, bctx, zpad, H1buf);
  hipLaunchKernelGGL(gemm2_k, dim3(MT / 64), dim3(256), 0, stream, H1buf, W2b, b2, RPR);
  hipLaunchKernelGGL(trans_k, dim3(B_), dim3(256), 0, stream, RPR, TRANS);
  hipLaunchKernelGGL(final_k, dim3(B_), dim3(128), 0, stream,
                     table, Wv, bv, Wc, bc, bev, bdist, bfeat, TRANS, out);
}

// Round 3
// 223.813 us; speedup vs baseline: 1.3074x; 1.1258x over previous
//
#include <hip/hip_runtime.h>
#include <hip/hip_bf16.h>

#define B_    512
#define N_    128
#define E_    300
#define EP    304      // component length padded to 38*8 (16B-chunk aligned)
#define CE    1200
#define KP1   1216     // 4 * EP
#define H1_   512
#define H2_   256
#define MT    66048    // 512 * 129 rows
#define VP1   50001
#define NTT   (VP1 * 38)      // table us8-chunks
#define NTW1  (H1_ * 152)     // W1p us8-chunks
#define NTW2  (H2_ * H1_ / 8) // W2b us8-chunks

typedef __attribute__((ext_vector_type(8))) short bf16x8;
typedef __attribute__((ext_vector_type(4))) float f32x4;
typedef __attribute__((ext_vector_type(4))) unsigned short us4;
typedef __attribute__((ext_vector_type(8))) unsigned short us8;

static __device__ __forceinline__ unsigned short f2bf(float f) {
  unsigned int u = __float_as_uint(f);
  u += 0x7fffu + ((u >> 16) & 1u);        // RNE
  return (unsigned short)(u >> 16);
}
static __device__ __forceinline__ float bf2f(unsigned short h) {
  return __uint_as_float(((unsigned int)h) << 16);
}
static __device__ __forceinline__ void gl16(const void* g, void* l) {
  __builtin_amdgcn_global_load_lds((const __attribute__((address_space(1))) unsigned int*)g,
                                   (__attribute__((address_space(3))) unsigned int*)l, 16, 0, 0);
}

// ---------------------------------------------------------------- fp32->bf16 repack (padded)
__global__ __launch_bounds__(256) void convert_k(
    const float* __restrict__ table, const float* __restrict__ W1, const float* __restrict__ W2,
    unsigned short* __restrict__ tbp, unsigned short* __restrict__ W1p,
    unsigned short* __restrict__ W2b) {
  int i = blockIdx.x * 256 + threadIdx.x;
  if (i < NTT) {
    int r = i / 38, ch = i - r * 38;
    int e = ch * 8;
    us8 o;
    if (e < 296) {
      float4 a = *reinterpret_cast<const float4*>(table + (size_t)r * 300 + e);
      float4 b = *reinterpret_cast<const float4*>(table + (size_t)r * 300 + e + 4);
      o[0]=f2bf(a.x); o[1]=f2bf(a.y); o[2]=f2bf(a.z); o[3]=f2bf(a.w);
      o[4]=f2bf(b.x); o[5]=f2bf(b.y); o[6]=f2bf(b.z); o[7]=f2bf(b.w);
    } else {
      float4 a = *reinterpret_cast<const float4*>(table + (size_t)r * 300 + 296);
      o[0]=f2bf(a.x); o[1]=f2bf(a.y); o[2]=f2bf(a.z); o[3]=f2bf(a.w);
      o[4]=0; o[5]=0; o[6]=0; o[7]=0;
    }
    *reinterpret_cast<us8*>(tbp + (size_t)r * EP + e) = o;
  } else if (i < NTT + NTW1) {
    int j = i - NTT;
    int r = j / 152, ch = j - r * 152;
    int k = ch * 8;
    int c = (k >= 912) ? 3 : (k >= 608) ? 2 : (k >= 304) ? 1 : 0;
    int e = k - c * EP;
    const float* src = W1 + (size_t)r * CE + c * 300 + e;
    us8 o;
    if (e < 296) {
      float4 a = *reinterpret_cast<const float4*>(src);
      float4 b = *reinterpret_cast<const float4*>(src + 4);
      o[0]=f2bf(a.x); o[1]=f2bf(a.y); o[2]=f2bf(a.z); o[3]=f2bf(a.w);
      o[4]=f2bf(b.x); o[5]=f2bf(b.y); o[6]=f2bf(b.z); o[7]=f2bf(b.w);
    } else {
      float4 a = *reinterpret_cast<const float4*>(src);
      o[0]=f2bf(a.x); o[1]=f2bf(a.y); o[2]=f2bf(a.z); o[3]=f2bf(a.w);
      o[4]=0; o[5]=0; o[6]=0; o[7]=0;
    }
    *reinterpret_cast<us8*>(W1p + (size_t)r * KP1 + k) = o;
  } else if (i < NTT + NTW1 + NTW2) {
    int j = i - NTT - NTW1;
    float4 a = *reinterpret_cast<const float4*>(W2 + (size_t)j * 8);
    float4 b = *reinterpret_cast<const float4*>(W2 + (size_t)j * 8 + 4);
    us8 o;
    o[0]=f2bf(a.x); o[1]=f2bf(a.y); o[2]=f2bf(a.z); o[3]=f2bf(a.w);
    o[4]=f2bf(b.x); o[5]=f2bf(b.y); o[6]=f2bf(b.z); o[7]=f2bf(b.w);
    *reinterpret_cast<us8*>(W2b + (size_t)j * 8) = o;
  }
}

// ---------------------------------------------------------------- GEMM1: gather + X@W1p^T, relu
// tile 128M x 256N, BK=32, 512 threads = 8 waves (2x4), wave -> 64x64, 2-phase dbuf.
__global__ __launch_bounds__(512) void gemm1_k(
    const unsigned short* __restrict__ tbp, const unsigned short* __restrict__ W1p,
    const float* __restrict__ b1, const int* __restrict__ bev, const int* __restrict__ bctx,
    unsigned short* __restrict__ H1buf) {
  __shared__ unsigned short As[2][128 * 32];   // 8 KB each
  __shared__ unsigned short Bs[2][256 * 32];   // 16 KB each

  const int tid  = threadIdx.x;
  const int lane = tid & 63;
  const int w    = tid >> 6;
  const int wr   = w >> 2, wc = w & 3;
  int bid = blockIdx.x;
  bid = (bid & 7) * 129 + (bid >> 3);          // XCD swizzle, 1032 % 8 == 0 (bijective)
  const int m0 = (bid >> 1) * 128;
  const int n0 = (bid & 1) * 256;
  const int fr = lane & 15, fg = lane >> 4;

  // staging geometry (16B chunks, XOR-swizzled 16B position within 64B row slice)
  const int l16 = (tid & 3) ^ ((tid >> 3) & 3);
  const unsigned short* abase[4];
  {
    int mrow = m0 + (tid >> 2);
    int bidx = mrow / 129, nidx = mrow - bidx * 129;
    const int* p = (nidx < 128) ? bctx + ((size_t)bidx * 128 + nidx) * 4
                                : bev + (size_t)bidx * 4;
#pragma unroll
    for (int c = 0; c < 4; ++c) abase[c] = tbp + (size_t)p[c] * EP;
  }
  const int aoff = l16 * 8;
  const unsigned short* bsrc = W1p + (size_t)(n0 + (tid >> 2)) * KP1 + l16 * 8;
  const int p16f = fg ^ ((fr >> 1) & 3);

  f32x4 acc[4][4];
#pragma unroll
  for (int mi = 0; mi < 4; ++mi)
#pragma unroll
    for (int ni = 0; ni < 4; ++ni)
#pragma unroll
      for (int r = 0; r < 4; ++r) acc[mi][ni][r] = 0.f;

#define STAGE1(buf, k0s)                                                     \
  {                                                                          \
    int k_ = (k0s) + aoff;                                                   \
    int c_ = (k_ >= 912) ? 3 : (k_ >= 608) ? 2 : (k_ >= 304) ? 1 : 0;        \
    gl16(abase[c_] + (k_ - c_ * EP), &As[buf][w * 512]);                     \
    gl16(bsrc + (k0s), &Bs[buf][w * 512]);                                   \
    gl16(bsrc + 128 * KP1 + (k0s), &Bs[buf][4096 + w * 512]);                \
  }

  STAGE1(0, 0);
  __syncthreads();
  int cur = 0;
  for (int t = 0; t < 38; ++t) {
    if (t < 37) STAGE1(cur ^ 1, (t + 1) * 32);
    bf16x8 af[4], bfv[4];
#pragma unroll
    for (int mi = 0; mi < 4; ++mi)
      af[mi] = *reinterpret_cast<const bf16x8*>(&As[cur][(wr * 64 + mi * 16 + fr) * 32 + p16f * 8]);
#pragma unroll
    for (int ni = 0; ni < 4; ++ni)
      bfv[ni] = *reinterpret_cast<const bf16x8*>(&Bs[cur][(wc * 64 + ni * 16 + fr) * 32 + p16f * 8]);
#pragma unroll
    for (int mi = 0; mi < 4; ++mi)
#pragma unroll
      for (int ni = 0; ni < 4; ++ni)
        acc[mi][ni] = __builtin_amdgcn_mfma_f32_16x16x32_bf16(af[mi], bfv[ni], acc[mi][ni], 0, 0, 0);
    __syncthreads();
    cur ^= 1;
  }
#undef STAGE1

  float bb[4];
#pragma unroll
  for (int ni = 0; ni < 4; ++ni) bb[ni] = b1[n0 + wc * 64 + ni * 16 + fr];
#pragma unroll
  for (int mi = 0; mi < 4; ++mi)
#pragma unroll
    for (int ni = 0; ni < 4; ++ni)
#pragma unroll
      for (int r = 0; r < 4; ++r) {
        float v = fmaxf(acc[mi][ni][r] + bb[ni], 0.f);
        int row = m0 + wr * 64 + mi * 16 + fg * 4 + r;
        int col = n0 + wc * 64 + ni * 16 + fr;
        H1buf[(size_t)row * H1_ + col] = f2bf(v);
      }
}

// ---------------------------------------------------------------- GEMM2: H1@W2^T, relu
// tile 128M x 256N (full H2), BK=32, 512 threads = 8 waves (2x4), 2-phase dbuf.
__global__ __launch_bounds__(512) void gemm2_k(
    const unsigned short* __restrict__ H1buf, const unsigned short* __restrict__ W2b,
    const float* __restrict__ b2, unsigned short* __restrict__ RPR) {
  __shared__ unsigned short As[2][128 * 32];
  __shared__ unsigned short Bs[2][256 * 32];

  const int tid  = threadIdx.x;
  const int lane = tid & 63;
  const int w    = tid >> 6;
  const int wr   = w >> 2, wc = w & 3;
  const int m0   = blockIdx.x * 128;
  const int fr = lane & 15, fg = lane >> 4;

  const int l16 = (tid & 3) ^ ((tid >> 3) & 3);
  const unsigned short* asrc = H1buf + (size_t)(m0 + (tid >> 2)) * H1_ + l16 * 8;
  const unsigned short* bsrc = W2b + (size_t)(tid >> 2) * H1_ + l16 * 8;
  const int p16f = fg ^ ((fr >> 1) & 3);

  f32x4 acc[4][4];
#pragma unroll
  for (int mi = 0; mi < 4; ++mi)
#pragma unroll
    for (int ni = 0; ni < 4; ++ni)
#pragma unroll
      for (int r = 0; r < 4; ++r) acc[mi][ni][r] = 0.f;

#define STAGE2(buf, k0s)                                                     \
  {                                                                          \
    gl16(asrc + (k0s), &As[buf][w * 512]);                                   \
    gl16(bsrc + (k0s), &Bs[buf][w * 512]);                                   \
    gl16(bsrc + 128 * H1_ + (k0s), &Bs[buf][4096 + w * 512]);                \
  }

  STAGE2(0, 0);
  __syncthreads();
  int cur = 0;
  for (int t = 0; t < 16; ++t) {
    if (t < 15) STAGE2(cur ^ 1, (t + 1) * 32);
    bf16x8 af[4], bfv[4];
#pragma unroll
    for (int mi = 0; mi < 4; ++mi)
      af[mi] = *reinterpret_cast<const bf16x8*>(&As[cur][(wr * 64 + mi * 16 + fr) * 32 + p16f * 8]);
#pragma unroll
    for (int ni = 0; ni < 4; ++ni)
      bfv[ni] = *reinterpret_cast<const bf16x8*>(&Bs[cur][(wc * 64 + ni * 16 + fr) * 32 + p16f * 8]);
#pragma unroll
    for (int mi = 0; mi < 4; ++mi)
#pragma unroll
      for (int ni = 0; ni < 4; ++ni)
        acc[mi][ni] = __builtin_amdgcn_mfma_f32_16x16x32_bf16(af[mi], bfv[ni], acc[mi][ni], 0, 0, 0);
    __syncthreads();
    cur ^= 1;
  }
#undef STAGE2

  float bb[4];
#pragma unroll
  for (int ni = 0; ni < 4; ++ni) bb[ni] = b2[wc * 64 + ni * 16 + fr];
#pragma unroll
  for (int mi = 0; mi < 4; ++mi)
#pragma unroll
    for (int ni = 0; ni < 4; ++ni)
#pragma unroll
      for (int r = 0; r < 4; ++r) {
        float v = fmaxf(acc[mi][ni][r] + bb[ni], 0.f);
        int row = m0 + wr * 64 + mi * 16 + fg * 4 + r;
        int col = wc * 64 + ni * 16 + fr;
        RPR[(size_t)row * H2_ + col] = f2bf(v);
      }
}

// ---------------------------------------------------------------- cosine trans: [B,128]
__global__ __launch_bounds__(256) void trans_k(const unsigned short* __restrict__ RPR,
                                               float* __restrict__ TRANS) {
  const int b = blockIdx.x, tid = threadIdx.x, lane = tid & 63, w = tid >> 6;
  const unsigned short* ev = RPR + ((size_t)b * 129 + 128) * H2_;
  us4 e4 = *reinterpret_cast<const us4*>(&ev[lane * 4]);
  float e0 = bf2f(e4[0]), e1 = bf2f(e4[1]), e2 = bf2f(e4[2]), e3 = bf2f(e4[3]);
  float ess = e0 * e0 + e1 * e1 + e2 * e2 + e3 * e3;
#pragma unroll
  for (int off = 32; off; off >>= 1) ess += __shfl_xor(ess, off);
  const float inv_e = 1.f / fmaxf(sqrtf(ess), 1e-12f);

  for (int n = w; n < 128; n += 4) {
    const unsigned short* cv = RPR + ((size_t)b * 129 + n) * H2_;
    us4 c4 = *reinterpret_cast<const us4*>(&cv[lane * 4]);
    float c0 = bf2f(c4[0]), c1 = bf2f(c4[1]), c2 = bf2f(c4[2]), c3 = bf2f(c4[3]);
    float dot = c0 * e0 + c1 * e1 + c2 * e2 + c3 * e3;
    float ss  = c0 * c0 + c1 * c1 + c2 * c2 + c3 * c3;
#pragma unroll
    for (int off = 32; off; off >>= 1) {
      dot += __shfl_xor(dot, off);
      ss  += __shfl_xor(ss, off);
    }
    if (lane == 0)
      TRANS[b * 128 + n] = dot * inv_e * (1.f / fmaxf(sqrtf(ss), 1e-12f));
  }
}

// ---------------------------------------------------------------- final
__global__ __launch_bounds__(128) void final_k(
    const float* __restrict__ table, const float* __restrict__ Wv, const float* __restrict__ bv,
    const float* __restrict__ Wc, const float* __restrict__ bc, const int* __restrict__ bev,
    const float* __restrict__ bdist, const float* __restrict__ bfeat,
    const float* __restrict__ TRANS, float* __restrict__ out) {
  const int b = blockIdx.x, tid = threadIdx.x;
  __shared__ float pred[E_];
  __shared__ float var_s[9];
  __shared__ float pool_s[2][11];

  const float MU[11]  = {1.0f, 0.9f, 0.7f, 0.5f, 0.3f, 0.1f, -0.1f, -0.3f, -0.5f, -0.7f, -0.9f};
  const float IS2[11] = {500000.f, 50.f, 50.f, 50.f, 50.f, 50.f, 50.f, 50.f, 50.f, 50.f, 50.f};

  const int prow = bev[b * 4 + 1];
  for (int e = tid; e < E_; e += 128) pred[e] = table[(size_t)prow * E_ + e];
  __syncthreads();

  if (tid < 9) {
    float s = bv[tid];
    for (int e = 0; e < E_; ++e) s += pred[e] * Wv[tid * E_ + e];
    var_s[tid] = fmaxf(s, 0.f) + log1pf(expf(-fabsf(s)));   // softplus
  }

  float t = TRANS[b * 128 + tid];
  float kv[11];
#pragma unroll
  for (int kk = 0; kk < 11; ++kk) {
    float u = t - MU[kk];
    kv[kk] = expf(-u * u * IS2[kk]);
  }
#pragma unroll
  for (int off = 32; off; off >>= 1)
#pragma unroll
    for (int kk = 0; kk < 11; ++kk) kv[kk] += __shfl_xor(kv[kk], off);
  const int w = tid >> 6, lane = tid & 63;
  if (lane == 0)
#pragma unroll
    for (int kk = 0; kk < 11; ++kk) pool_s[w][kk] = kv[kk];
  __syncthreads();

  if (tid == 0) {
    float score = bc[0];
    for (int j = 0; j < 9; ++j) {
      float d = bdist[b * 9 + j];
      score += Wc[j] * expf(-(d * d) / var_s[j]);
    }
    for (int i = 0; i < 8; ++i) score += Wc[9 + i] * bfeat[b * 8 + i];
    for (int kk = 0; kk < 11; ++kk) {
      float p = fmaxf(pool_s[0][kk] + pool_s[1][kk], 1e-10f);
      score += Wc[17 + kk] * (0.01f * logf(p));
    }
    out[b] = 1.f / (1.f + expf(-score));
  }
}

// ----------------------------------------------------------------
extern "C" void kernel_launch(void* const* d_in, const int* in_sizes, int n_in,
                              void* d_out, int out_size, void* d_ws, size_t ws_size,
                              hipStream_t stream) {
  const float* table = (const float*)d_in[0];
  const float* W1    = (const float*)d_in[1];
  const float* b1    = (const float*)d_in[2];
  const float* W2    = (const float*)d_in[3];
  const float* b2    = (const float*)d_in[4];
  const float* Wv    = (const float*)d_in[5];
  const float* bv    = (const float*)d_in[6];
  const float* Wc    = (const float*)d_in[7];
  const float* bc    = (const float*)d_in[8];
  const int*   bev   = (const int*)d_in[9];
  const float* bfeat = (const float*)d_in[10];
  const float* bdist = (const float*)d_in[11];
  const int*   bctx  = (const int*)d_in[12];
  float* out = (float*)d_out;

  auto align64 = [](size_t x) { return (x + 63) & ~(size_t)63; };
  size_t off = 0;
  size_t o_tbp = off; off += align64((size_t)VP1 * EP * 2);        // 30.4 MB
  size_t o_W1p = off; off += align64((size_t)H1_ * KP1 * 2);       //  1.25 MB
  size_t o_W2b = off; off += align64((size_t)H2_ * H1_ * 2);       //  0.26 MB
  size_t o_H1  = off; off += align64((size_t)MT * H1_ * 2);        // 67.6 MB
  size_t o_RPR = off; off += align64((size_t)MT * H2_ * 2);        // 33.8 MB
  size_t o_TR  = off; off += align64((size_t)B_ * N_ * 4);         //  0.26 MB
  if (ws_size < off) {                       // loud, distinguishable failure
    hipMemsetAsync(d_out, 0xBF, (size_t)out_size * 4, stream);
    return;
  }
  char* ws = (char*)d_ws;
  unsigned short* tbp   = (unsigned short*)(ws + o_tbp);
  unsigned short* W1p   = (unsigned short*)(ws + o_W1p);
  unsigned short* W2b   = (unsigned short*)(ws + o_W2b);
  unsigned short* H1buf = (unsigned short*)(ws + o_H1);
  unsigned short* RPR   = (unsigned short*)(ws + o_RPR);
  float*          TRANS = (float*)(ws + o_TR);

  const int conv_items = NTT + NTW1 + NTW2;
  hipLaunchKernelGGL(convert_k, dim3((conv_items + 255) / 256), dim3(256), 0, stream,
                     table, W1, W2, tbp, W1p, W2b);
  hipLaunchKernelGGL(gemm1_k, dim3(MT / 128 * 2), dim3(512), 0, stream,
                     tbp, W1p, b1, bev, bctx, H1buf);
  hipLaunchKernelGGL(gemm2_k, dim3(MT / 128), dim3(512), 0, stream, H1buf, W2b, b2, RPR);
  hipLaunchKernelGGL(trans_k, dim3(B_), dim3(256), 0, stream, RPR, TRANS);
  hipLaunchKernelGGL(final_k, dim3(B_), dim3(128), 0, stream,
                     table, Wv, bv, Wc, bc, bev, bdist, bfeat, TRANS, out);
}

// Round 4
// 205.328 us; speedup vs baseline: 1.4251x; 1.0900x over previous
//
#include <hip/hip_runtime.h>
#include <hip/hip_bf16.h>

#define B_    512
#define N_    128
#define E_    300
#define EP    304      // component length padded to 38*8 (16B-chunk aligned)
#define CE    1200
#define KP1   1216     // 4 * EP
#define H1_   512
#define H2_   256
#define MT    66048    // 512 * 129 rows
#define VP1   50001
#define NTT   (VP1 * 38)      // table us8-chunks
#define NTW1  (H1_ * 152)     // W1p us8-chunks
#define NTW2  (H2_ * H1_ / 8) // W2b us8-chunks

typedef __attribute__((ext_vector_type(8))) short bf16x8;
typedef __attribute__((ext_vector_type(4))) float f32x4;
typedef __attribute__((ext_vector_type(4))) unsigned short us4;
typedef __attribute__((ext_vector_type(8))) unsigned short us8;

static __device__ __forceinline__ unsigned short f2bf(float f) {
  unsigned int u = __float_as_uint(f);
  u += 0x7fffu + ((u >> 16) & 1u);        // RNE
  return (unsigned short)(u >> 16);
}
static __device__ __forceinline__ float bf2f(unsigned short h) {
  return __uint_as_float(((unsigned int)h) << 16);
}
static __device__ __forceinline__ void gl16(const void* g, void* l) {
  __builtin_amdgcn_global_load_lds((const __attribute__((address_space(1))) unsigned int*)g,
                                   (__attribute__((address_space(3))) unsigned int*)l, 16, 0, 0);
}

// ---------------------------------------------------------------- fp32->bf16 repack (padded)
__global__ __launch_bounds__(256) void convert_k(
    const float* __restrict__ table, const float* __restrict__ W1, const float* __restrict__ W2,
    unsigned short* __restrict__ tbp, unsigned short* __restrict__ W1p,
    unsigned short* __restrict__ W2b) {
  int i = blockIdx.x * 256 + threadIdx.x;
  if (i < NTT) {
    int r = i / 38, ch = i - r * 38;
    int e = ch * 8;
    us8 o;
    if (e < 296) {
      float4 a = *reinterpret_cast<const float4*>(table + (size_t)r * 300 + e);
      float4 b = *reinterpret_cast<const float4*>(table + (size_t)r * 300 + e + 4);
      o[0]=f2bf(a.x); o[1]=f2bf(a.y); o[2]=f2bf(a.z); o[3]=f2bf(a.w);
      o[4]=f2bf(b.x); o[5]=f2bf(b.y); o[6]=f2bf(b.z); o[7]=f2bf(b.w);
    } else {
      float4 a = *reinterpret_cast<const float4*>(table + (size_t)r * 300 + 296);
      o[0]=f2bf(a.x); o[1]=f2bf(a.y); o[2]=f2bf(a.z); o[3]=f2bf(a.w);
      o[4]=0; o[5]=0; o[6]=0; o[7]=0;
    }
    *reinterpret_cast<us8*>(tbp + (size_t)r * EP + e) = o;
  } else if (i < NTT + NTW1) {
    int j = i - NTT;
    int r = j / 152, ch = j - r * 152;
    int k = ch * 8;
    int c = (k >= 912) ? 3 : (k >= 608) ? 2 : (k >= 304) ? 1 : 0;
    int e = k - c * EP;
    const float* src = W1 + (size_t)r * CE + c * 300 + e;
    us8 o;
    if (e < 296) {
      float4 a = *reinterpret_cast<const float4*>(src);
      float4 b = *reinterpret_cast<const float4*>(src + 4);
      o[0]=f2bf(a.x); o[1]=f2bf(a.y); o[2]=f2bf(a.z); o[3]=f2bf(a.w);
      o[4]=f2bf(b.x); o[5]=f2bf(b.y); o[6]=f2bf(b.z); o[7]=f2bf(b.w);
    } else {
      float4 a = *reinterpret_cast<const float4*>(src);
      o[0]=f2bf(a.x); o[1]=f2bf(a.y); o[2]=f2bf(a.z); o[3]=f2bf(a.w);
      o[4]=0; o[5]=0; o[6]=0; o[7]=0;
    }
    *reinterpret_cast<us8*>(W1p + (size_t)r * KP1 + k) = o;
  } else if (i < NTT + NTW1 + NTW2) {
    int j = i - NTT - NTW1;
    float4 a = *reinterpret_cast<const float4*>(W2 + (size_t)j * 8);
    float4 b = *reinterpret_cast<const float4*>(W2 + (size_t)j * 8 + 4);
    us8 o;
    o[0]=f2bf(a.x); o[1]=f2bf(a.y); o[2]=f2bf(a.z); o[3]=f2bf(a.w);
    o[4]=f2bf(b.x); o[5]=f2bf(b.y); o[6]=f2bf(b.z); o[7]=f2bf(b.w);
    *reinterpret_cast<us8*>(W2b + (size_t)j * 8) = o;
  }
}

// ---------------------------------------------------------------- GEMM1: gather + X@W1p^T, relu
// tile 128M x 256N, BK=32, 512 threads = 8 waves (2x4), depth-3 pipeline, counted vmcnt.
__global__ __launch_bounds__(512) void gemm1_k(
    const unsigned short* __restrict__ tbp, const unsigned short* __restrict__ W1p,
    const float* __restrict__ b1, const int* __restrict__ bev, const int* __restrict__ bctx,
    unsigned short* __restrict__ H1buf) {
  __shared__ unsigned short As[3][128 * 32];   //  8 KB each
  __shared__ unsigned short Bs[3][256 * 32];   // 16 KB each -> 72 KB total

  const int tid  = threadIdx.x;
  const int lane = tid & 63;
  const int w    = tid >> 6;
  const int wr   = w >> 2, wc = w & 3;
  int bid = blockIdx.x;
  bid = (bid & 7) * 129 + (bid >> 3);          // XCD swizzle, 1032 % 8 == 0 (bijective)
  const int m0 = (bid >> 1) * 128;
  const int n0 = (bid & 1) * 256;
  const int fr = lane & 15, fg = lane >> 4;

  // staging geometry (16B chunks, XOR-swizzled 16B position within 64B row slice)
  const int l16 = (tid & 3) ^ ((tid >> 3) & 3);
  const unsigned short* abase[4];
  {
    int mrow = m0 + (tid >> 2);
    int bidx = mrow / 129, nidx = mrow - bidx * 129;
    const int* p = (nidx < 128) ? bctx + ((size_t)bidx * 128 + nidx) * 4
                                : bev + (size_t)bidx * 4;
#pragma unroll
    for (int c = 0; c < 4; ++c) abase[c] = tbp + (size_t)p[c] * EP;
  }
  const int aoff = l16 * 8;
  const unsigned short* bsrc = W1p + (size_t)(n0 + (tid >> 2)) * KP1 + l16 * 8;
  const int p16f = fg ^ ((fr >> 1) & 3);

  f32x4 acc[4][4];
#pragma unroll
  for (int mi = 0; mi < 4; ++mi)
#pragma unroll
    for (int ni = 0; ni < 4; ++ni)
#pragma unroll
      for (int r = 0; r < 4; ++r) acc[mi][ni][r] = 0.f;

#define STAGE1(buf, k0s)                                                     \
  {                                                                          \
    int k_ = (k0s) + aoff;                                                   \
    int c_ = (k_ >= 912) ? 3 : (k_ >= 608) ? 2 : (k_ >= 304) ? 1 : 0;        \
    gl16(abase[c_] + (k_ - c_ * EP), &As[buf][w * 512]);                     \
    gl16(bsrc + (k0s), &Bs[buf][w * 512]);                                   \
    gl16(bsrc + 128 * KP1 + (k0s), &Bs[buf][4096 + w * 512]);                \
  }

#define COMPUTE1(buf)                                                        \
  {                                                                          \
    bf16x8 af[4], bfv[4];                                                    \
    _Pragma("unroll")                                                        \
    for (int mi = 0; mi < 4; ++mi)                                           \
      af[mi] = *reinterpret_cast<const bf16x8*>(                             \
          &As[buf][(wr * 64 + mi * 16 + fr) * 32 + p16f * 8]);               \
    _Pragma("unroll")                                                        \
    for (int ni = 0; ni < 4; ++ni)                                           \
      bfv[ni] = *reinterpret_cast<const bf16x8*>(                            \
          &Bs[buf][(wc * 64 + ni * 16 + fr) * 32 + p16f * 8]);               \
    __builtin_amdgcn_s_setprio(1);                                           \
    _Pragma("unroll")                                                        \
    for (int mi = 0; mi < 4; ++mi)                                           \
      _Pragma("unroll")                                                      \
      for (int ni = 0; ni < 4; ++ni)                                         \
        acc[mi][ni] = __builtin_amdgcn_mfma_f32_16x16x32_bf16(               \
            af[mi], bfv[ni], acc[mi][ni], 0, 0, 0);                          \
    __builtin_amdgcn_s_setprio(0);                                           \
  }

  STAGE1(0, 0);
  STAGE1(1, 32);
  int cur = 0, nx = 2;
  for (int t = 0; t < 37; ++t) {
    asm volatile("s_waitcnt vmcnt(3)" ::: "memory");   // stage(t) landed; stage(t+1) may fly
    __builtin_amdgcn_s_barrier();                      // all waves: stage(t) in LDS, compute(t-1) done
    if (t + 2 < 38) STAGE1(nx, (t + 2) * 32);
    COMPUTE1(cur);
    cur = (cur == 2) ? 0 : cur + 1;
    nx  = (nx  == 2) ? 0 : nx  + 1;
  }
  asm volatile("s_waitcnt vmcnt(0)" ::: "memory");
  __builtin_amdgcn_s_barrier();
  COMPUTE1(cur);
#undef STAGE1
#undef COMPUTE1

  float bb[4];
#pragma unroll
  for (int ni = 0; ni < 4; ++ni) bb[ni] = b1[n0 + wc * 64 + ni * 16 + fr];
#pragma unroll
  for (int mi = 0; mi < 4; ++mi)
#pragma unroll
    for (int ni = 0; ni < 4; ++ni)
#pragma unroll
      for (int r = 0; r < 4; ++r) {
        float v = fmaxf(acc[mi][ni][r] + bb[ni], 0.f);
        int row = m0 + wr * 64 + mi * 16 + fg * 4 + r;
        int col = n0 + wc * 64 + ni * 16 + fr;
        H1buf[(size_t)row * H1_ + col] = f2bf(v);
      }
}

// ---------------------------------------------------------------- GEMM2: H1@W2^T, relu
// tile 128M x 256N (full H2), BK=32, 512 threads, depth-3 pipeline, counted vmcnt.
__global__ __launch_bounds__(512) void gemm2_k(
    const unsigned short* __restrict__ H1buf, const unsigned short* __restrict__ W2b,
    const float* __restrict__ b2, unsigned short* __restrict__ RPR) {
  __shared__ unsigned short As[3][128 * 32];
  __shared__ unsigned short Bs[3][256 * 32];

  const int tid  = threadIdx.x;
  const int lane = tid & 63;
  const int w    = tid >> 6;
  const int wr   = w >> 2, wc = w & 3;
  const int m0   = blockIdx.x * 128;
  const int fr = lane & 15, fg = lane >> 4;

  const int l16 = (tid & 3) ^ ((tid >> 3) & 3);
  const unsigned short* asrc = H1buf + (size_t)(m0 + (tid >> 2)) * H1_ + l16 * 8;
  const unsigned short* bsrc = W2b + (size_t)(tid >> 2) * H1_ + l16 * 8;
  const int p16f = fg ^ ((fr >> 1) & 3);

  f32x4 acc[4][4];
#pragma unroll
  for (int mi = 0; mi < 4; ++mi)
#pragma unroll
    for (int ni = 0; ni < 4; ++ni)
#pragma unroll
      for (int r = 0; r < 4; ++r) acc[mi][ni][r] = 0.f;

#define STAGE2(buf, k0s)                                                     \
  {                                                                          \
    gl16(asrc + (k0s), &As[buf][w * 512]);                                   \
    gl16(bsrc + (k0s), &Bs[buf][w * 512]);                                   \
    gl16(bsrc + 128 * H1_ + (k0s), &Bs[buf][4096 + w * 512]);                \
  }

#define COMPUTE2(buf)                                                        \
  {                                                                          \
    bf16x8 af[4], bfv[4];                                                    \
    _Pragma("unroll")                                                        \
    for (int mi = 0; mi < 4; ++mi)                                           \
      af[mi] = *reinterpret_cast<const bf16x8*>(                             \
          &As[buf][(wr * 64 + mi * 16 + fr) * 32 + p16f * 8]);               \
    _Pragma("unroll")                                                        \
    for (int ni = 0; ni < 4; ++ni)                                           \
      bfv[ni] = *reinterpret_cast<const bf16x8*>(                            \
          &Bs[buf][(wc * 64 + ni * 16 + fr) * 32 + p16f * 8]);               \
    __builtin_amdgcn_s_setprio(1);                                           \
    _Pragma("unroll")                                                        \
    for (int mi = 0; mi < 4; ++mi)                                           \
      _Pragma("unroll")                                                      \
      for (int ni = 0; ni < 4; ++ni)                                         \
        acc[mi][ni] = __builtin_amdgcn_mfma_f32_16x16x32_bf16(               \
            af[mi], bfv[ni], acc[mi][ni], 0, 0, 0);                          \
    __builtin_amdgcn_s_setprio(0);                                           \
  }

  STAGE2(0, 0);
  STAGE2(1, 32);
  int cur = 0, nx = 2;
  for (int t = 0; t < 15; ++t) {
    asm volatile("s_waitcnt vmcnt(3)" ::: "memory");
    __builtin_amdgcn_s_barrier();
    if (t + 2 < 16) STAGE2(nx, (t + 2) * 32);
    COMPUTE2(cur);
    cur = (cur == 2) ? 0 : cur + 1;
    nx  = (nx  == 2) ? 0 : nx  + 1;
  }
  asm volatile("s_waitcnt vmcnt(0)" ::: "memory");
  __builtin_amdgcn_s_barrier();
  COMPUTE2(cur);
#undef STAGE2
#undef COMPUTE2

  float bb[4];
#pragma unroll
  for (int ni = 0; ni < 4; ++ni) bb[ni] = b2[wc * 64 + ni * 16 + fr];
#pragma unroll
  for (int mi = 0; mi < 4; ++mi)
#pragma unroll
    for (int ni = 0; ni < 4; ++ni)
#pragma unroll
      for (int r = 0; r < 4; ++r) {
        float v = fmaxf(acc[mi][ni][r] + bb[ni], 0.f);
        int row = m0 + wr * 64 + mi * 16 + fg * 4 + r;
        int col = wc * 64 + ni * 16 + fr;
        RPR[(size_t)row * H2_ + col] = f2bf(v);
      }
}

// ---------------------------------------------------------------- cosine trans: [B,128]
__global__ __launch_bounds__(256) void trans_k(const unsigned short* __restrict__ RPR,
                                               float* __restrict__ TRANS) {
  const int b = blockIdx.x, tid = threadIdx.x, lane = tid & 63, w = tid >> 6;
  const unsigned short* ev = RPR + ((size_t)b * 129 + 128) * H2_;
  us4 e4 = *reinterpret_cast<const us4*>(&ev[lane * 4]);
  float e0 = bf2f(e4[0]), e1 = bf2f(e4[1]), e2 = bf2f(e4[2]), e3 = bf2f(e4[3]);
  float ess = e0 * e0 + e1 * e1 + e2 * e2 + e3 * e3;
#pragma unroll
  for (int off = 32; off; off >>= 1) ess += __shfl_xor(ess, off);
  const float inv_e = 1.f / fmaxf(sqrtf(ess), 1e-12f);

  for (int n = w; n < 128; n += 4) {
    const unsigned short* cv = RPR + ((size_t)b * 129 + n) * H2_;
    us4 c4 = *reinterpret_cast<const us4*>(&cv[lane * 4]);
    float c0 = bf2f(c4[0]), c1 = bf2f(c4[1]), c2 = bf2f(c4[2]), c3 = bf2f(c4[3]);
    float dot = c0 * e0 + c1 * e1 + c2 * e2 + c3 * e3;
    float ss  = c0 * c0 + c1 * c1 + c2 * c2 + c3 * c3;
#pragma unroll
    for (int off = 32; off; off >>= 1) {
      dot += __shfl_xor(dot, off);
      ss  += __shfl_xor(ss, off);
    }
    if (lane == 0)
      TRANS[b * 128 + n] = dot * inv_e * (1.f / fmaxf(sqrtf(ss), 1e-12f));
  }
}

// ---------------------------------------------------------------- final
__global__ __launch_bounds__(128) void final_k(
    const float* __restrict__ table, const float* __restrict__ Wv, const float* __restrict__ bv,
    const float* __restrict__ Wc, const float* __restrict__ bc, const int* __restrict__ bev,
    const float* __restrict__ bdist, const float* __restrict__ bfeat,
    const float* __restrict__ TRANS, float* __restrict__ out) {
  const int b = blockIdx.x, tid = threadIdx.x;
  __shared__ float pred[E_];
  __shared__ float var_s[9];
  __shared__ float pool_s[2][11];

  const float MU[11]  = {1.0f, 0.9f, 0.7f, 0.5f, 0.3f, 0.1f, -0.1f, -0.3f, -0.5f, -0.7f, -0.9f};
  const float IS2[11] = {500000.f, 50.f, 50.f, 50.f, 50.f, 50.f, 50.f, 50.f, 50.f, 50.f, 50.f};

  const int prow = bev[b * 4 + 1];
  for (int e = tid; e < E_; e += 128) pred[e] = table[(size_t)prow * E_ + e];
  __syncthreads();

  if (tid < 9) {
    float s = bv[tid];
    for (int e = 0; e < E_; ++e) s += pred[e] * Wv[tid * E_ + e];
    var_s[tid] = fmaxf(s, 0.f) + log1pf(expf(-fabsf(s)));   // softplus
  }

  float t = TRANS[b * 128 + tid];
  float kv[11];
#pragma unroll
  for (int kk = 0; kk < 11; ++kk) {
    float u = t - MU[kk];
    kv[kk] = expf(-u * u * IS2[kk]);
  }
#pragma unroll
  for (int off = 32; off; off >>= 1)
#pragma unroll
    for (int kk = 0; kk < 11; ++kk) kv[kk] += __shfl_xor(kv[kk], off);
  const int w = tid >> 6, lane = tid & 63;
  if (lane == 0)
#pragma unroll
    for (int kk = 0; kk < 11; ++kk) pool_s[w][kk] = kv[kk];
  __syncthreads();

  if (tid == 0) {
    float score = bc[0];
    for (int j = 0; j < 9; ++j) {
      float d = bdist[b * 9 + j];
      score += Wc[j] * expf(-(d * d) / var_s[j]);
    }
    for (int i = 0; i < 8; ++i) score += Wc[9 + i] * bfeat[b * 8 + i];
    for (int kk = 0; kk < 11; ++kk) {
      float p = fmaxf(pool_s[0][kk] + pool_s[1][kk], 1e-10f);
      score += Wc[17 + kk] * (0.01f * logf(p));
    }
    out[b] = 1.f / (1.f + expf(-score));
  }
}

// ----------------------------------------------------------------
extern "C" void kernel_launch(void* const* d_in, const int* in_sizes, int n_in,
                              void* d_out, int out_size, void* d_ws, size_t ws_size,
                              hipStream_t stream) {
  const float* table = (const float*)d_in[0];
  const float* W1    = (const float*)d_in[1];
  const float* b1    = (const float*)d_in[2];
  const float* W2    = (const float*)d_in[3];
  const float* b2    = (const float*)d_in[4];
  const float* Wv    = (const float*)d_in[5];
  const float* bv    = (const float*)d_in[6];
  const float* Wc    = (const float*)d_in[7];
  const float* bc    = (const float*)d_in[8];
  const int*   bev   = (const int*)d_in[9];
  const float* bfeat = (const float*)d_in[10];
  const float* bdist = (const float*)d_in[11];
  const int*   bctx  = (const int*)d_in[12];
  float* out = (float*)d_out;

  auto align64 = [](size_t x) { return (x + 63) & ~(size_t)63; };
  size_t off = 0;
  size_t o_tbp = off; off += align64((size_t)VP1 * EP * 2);        // 30.4 MB
  size_t o_W1p = off; off += align64((size_t)H1_ * KP1 * 2);       //  1.25 MB
  size_t o_W2b = off; off += align64((size_t)H2_ * H1_ * 2);       //  0.26 MB
  size_t o_H1  = off; off += align64((size_t)MT * H1_ * 2);        // 67.6 MB
  size_t o_RPR = off; off += align64((size_t)MT * H2_ * 2);        // 33.8 MB
  size_t o_TR  = off; off += align64((size_t)B_ * N_ * 4);         //  0.26 MB
  if (ws_size < off) {                       // loud, distinguishable failure
    hipMemsetAsync(d_out, 0xBF, (size_t)out_size * 4, stream);
    return;
  }
  char* ws = (char*)d_ws;
  unsigned short* tbp   = (unsigned short*)(ws + o_tbp);
  unsigned short* W1p   = (unsigned short*)(ws + o_W1p);
  unsigned short* W2b   = (unsigned short*)(ws + o_W2b);
  unsigned short* H1buf = (unsigned short*)(ws + o_H1);
  unsigned short* RPR   = (unsigned short*)(ws + o_RPR);
  float*          TRANS = (float*)(ws + o_TR);

  const int conv_items = NTT + NTW1 + NTW2;
  hipLaunchKernelGGL(convert_k, dim3((conv_items + 255) / 256), dim3(256), 0, stream,
                     table, W1, W2, tbp, W1p, W2b);
  hipLaunchKernelGGL(gemm1_k, dim3(MT / 128 * 2), dim3(512), 0, stream,
                     tbp, W1p, b1, bev, bctx, H1buf);
  hipLaunchKernelGGL(gemm2_k, dim3(MT / 128), dim3(512), 0, stream, H1buf, W2b, b2, RPR);
  hipLaunchKernelGGL(trans_k, dim3(B_), dim3(256), 0, stream, RPR, TRANS);
  hipLaunchKernelGGL(final_k, dim3(B_), dim3(128), 0, stream,
                     table, Wv, bv, Wc, bc, bev, bdist, bfeat, TRANS, out);
}